// Round 10
// baseline (118.661 us; speedup 1.0000x reference)
//
#include <hip/hip_runtime.h>
#include <hip/hip_bf16.h>
#include <cstdint>

#define N_DIM 4096
#define K_DIM 2048           // i8 bytes per row
#define NKT 32               // 32 K-tiles of 64
#define QSCALE 24.0f
#define QINV (1.0f / 24.0f)

typedef float floatx4 __attribute__((ext_vector_type(4)));
typedef int intx4 __attribute__((ext_vector_type(4)));
typedef unsigned long long ull;

__device__ __forceinline__ void gld_lds16(const void* g, void* l) {
    __builtin_amdgcn_global_load_lds(
        (const __attribute__((address_space(1))) unsigned int*)g,
        (__attribute__((address_space(3))) unsigned int*)l,
        16, 0, 0);
}

// ---------------- Kernel 0: quantize fp32 -> int8 (scale 24), int row norms -
__global__ __launch_bounds__(256)
void prep_kernel(const float* __restrict__ X, char* __restrict__ Q,
                 int* __restrict__ sqi) {
    const int row = blockIdx.x;
    const int tid = threadIdx.x;
    const float* xr = X + (size_t)row * K_DIM;
    floatx4 a = *(const floatx4*)(xr + tid * 8);
    floatx4 b = *(const floatx4*)(xr + tid * 8 + 4);
    int s = 0;
    unsigned lo = 0, hi = 0;
#pragma unroll
    for (int e = 0; e < 4; ++e) {
        int v = __float2int_rn(a[e] * QSCALE);
        v = min(127, max(-127, v));
        s += v * v;
        lo |= ((unsigned)(v & 0xff)) << (8 * e);
        int w = __float2int_rn(b[e] * QSCALE);
        w = min(127, max(-127, w));
        s += w * w;
        hi |= ((unsigned)(w & 0xff)) << (8 * e);
    }
    *(int2*)(Q + (size_t)row * K_DIM + tid * 8) = make_int2((int)lo, (int)hi);
#pragma unroll
    for (int off = 32; off; off >>= 1) s += __shfl_down(s, off);
    __shared__ int wsum[4];
    const int wave = tid >> 6, lane = tid & 63;
    if (lane == 0) wsum[wave] = s;
    __syncthreads();
    if (tid == 0) sqi[row] = wsum[0] + wsum[1] + wsum[2] + wsum[3];
}

// ---------------- Kernel 1: 128x128 int8 MFMA GEMM + distance epilogue ------
// 256 thr = 4 waves (2Mx2N). Grid 1024 -> 3 blocks/CU co-resident
// (launch_bounds(256,3); LDS 48KB x3 = 144 <= 160): inter-block wave overlap
// hides LDS reads, vmcnt stalls, and the D-write burst (m97/m114 mechanism).
// Triple-buffered LDS, one K-tile (64B/row) per buffer:
//   iter t: STAGE(t+2 -> buf[(t+2)%3]) | read buf[t%3] (8 b128) |
//           16 MFMA | vmcnt(4) [retires stage(t+1)] | BAR
// WAR: stage(t+2) overwrites the buffer read at t-1; those reads completed
// before BAR(t-1) (lgkm before MFMA, MFMA before BAR) -> safe.
// LDS region layout (8KB per operand per buf): transposed 16B units,
// pos16 = ksub*128 + row (per-thread source addressing, linear gld dest);
// read bank-phase = row%8 -> conflict-free (R9-verified, 0 conflicts).
// Fragment layout (i8 16x16x64): lane holds 16 i8, row/col = lane&15,
// k = (lane>>4)*16 + [0..15]; C/D: col = lane&15, row = (lane>>4)*4 + r.
#define BAR() __builtin_amdgcn_s_barrier()
#define PRIO1() __builtin_amdgcn_s_setprio(1)
#define PRIO0() __builtin_amdgcn_s_setprio(0)
#define VMCNT4() asm volatile("s_waitcnt vmcnt(4)" ::: "memory")
#define VMCNT0() asm volatile("s_waitcnt vmcnt(0)" ::: "memory")
#define STAGE(KT, BB) { \
    gld_lds16(aSt + (KT) * 64,      lds + (BB) + widB); \
    gld_lds16(aSt + (KT) * 64 + 32, lds + (BB) + 4096 + widB); \
    gld_lds16(bSt + (KT) * 64,      lds + (BB) + 8192 + widB); \
    gld_lds16(bSt + (KT) * 64 + 32, lds + (BB) + 12288 + widB); }

__global__ __launch_bounds__(256, 3)
void gemm_dist(const char* __restrict__ Q, const int* __restrict__ sqi,
               float* __restrict__ D) {
    __shared__ char lds[49152];   // 48 KB = 3 bufs x (A 8KB + B 8KB)
    const int tid = threadIdx.x;
    const int wid = tid >> 6, lane = tid & 63;
    const int wr = wid >> 1, wc = wid & 1;
    const int fr = lane & 15, ksub = lane >> 4;
    const int widB = wid * 1024;

    // read byte-offsets within an 8KB region
    int rA[4], rB[4];
#pragma unroll
    for (int m = 0; m < 4; ++m) rA[m] = (ksub * 128 + wr * 64 + m * 16 + fr) * 16;
#pragma unroll
    for (int n = 0; n < 4; ++n) rB[n] = (ksub * 128 + wc * 64 + n * 16 + fr) * 16;

    const int swz = (blockIdx.x & 7) * 128 + (blockIdx.x >> 3);  // XCD-chunked
    const int bi = swz >> 5, bj = swz & 31;
    const int rowC0 = bi * 128, colC0 = bj * 128;

    // staging source: thread t covers pos16 = t (issue0, ksub=t>>7) and
    // pos16 = 256+t (issue1, ksub=2+(t>>7)); row = t&127 for both.
    const int srow = tid & 127;
    const int sk = (tid >> 7) * 16;
    const char* aSt = Q + (size_t)(rowC0 + srow) * K_DIM + sk;
    const char* bSt = Q + (size_t)(colC0 + srow) * K_DIM + sk;

    intx4 acc[4][4];
#pragma unroll
    for (int a1 = 0; a1 < 4; ++a1)
#pragma unroll
    for (int a2 = 0; a2 < 4; ++a2) acc[a1][a2] = (intx4){0, 0, 0, 0};
    intx4 af[4], bfv[4];

    // prologue: stage t0 -> buf0, t1 -> buf1; vmcnt(4) = t0 landed
    STAGE(0, 0);
    STAGE(1, 16384);
    VMCNT4();
    BAR();

    int cb = 0;   // byte base of current buffer (0 / 16384 / 32768)
    for (int t = 0; t < NKT; ++t) {
        int sb = cb + 32768; if (sb >= 49152) sb -= 49152;   // (t+2)%3
        if (t < NKT - 2) STAGE(t + 2, sb);
#pragma unroll
        for (int m = 0; m < 4; ++m) af[m] = *(const intx4*)(lds + cb + rA[m]);
#pragma unroll
        for (int n = 0; n < 4; ++n) bfv[n] = *(const intx4*)(lds + cb + 8192 + rB[n]);
        PRIO1();
#pragma unroll
        for (int n = 0; n < 4; ++n)
#pragma unroll
        for (int m = 0; m < 4; ++m)
            acc[n][m] = __builtin_amdgcn_mfma_i32_16x16x64_i8(
                af[m], bfv[n], acc[n][m], 0, 0, 0);
        PRIO0();
        if (t < NKT - 2) { VMCNT4(); } else { VMCNT0(); }
        BAR();
        cb += 16384; if (cb >= 49152) cb = 0;
    }

    // epilogue: D[i][j] = (v>0) ? sqrt(v)/24 : 1e-6, v = sqi+sqj-2*dot (exact)
#pragma unroll
    for (int n = 0; n < 4; ++n) {
        const int col = colC0 + wc * 64 + n * 16 + fr;
        const int sqc = sqi[col];
#pragma unroll
        for (int m = 0; m < 4; ++m) {
            const int row0 = rowC0 + wr * 64 + m * 16 + ksub * 4;
#pragma unroll
            for (int r = 0; r < 4; ++r) {
                const int v = sqi[row0 + r] + sqc - 2 * acc[n][m][r];
                const float d = (v > 0) ? sqrtf((float)v) * QINV : 1e-6f;
                D[(size_t)(row0 + r) * N_DIM + col] = d;
            }
        }
    }
}

// ---------------- Kernel 2: fused row stats + third-class scan + loss -------
__global__ __launch_bounds__(256)
void stats_loss(const float* __restrict__ D, const int* __restrict__ tgt,
                float* __restrict__ lossArr) {
    const int i = blockIdx.x, tid = threadIdx.x;
    const int ti = tgt[i];
    const float* row = D + (size_t)i * N_DIM;
    ull kmax = 0ULL, kmin = ~0ULL;
#pragma unroll
    for (int it = 0; it < 4; ++it) {
        const int j0 = (it * 256 + tid) * 4;
        floatx4 d = *(const floatx4*)(row + j0);
        intx4 t4 = *(const intx4*)(tgt + j0);
#pragma unroll
        for (int e = 0; e < 4; ++e) {
            const int j = j0 + e;
            const ull db = (ull)__float_as_uint(d[e]) << 32;
            if (t4[e] == ti) { ull k = db | (unsigned)j;  if (k > kmax) kmax = k; }
            else             { ull k = db | (unsigned)~j; if (k < kmin) kmin = k; }
        }
    }
    __shared__ ull sM[256], sN[256];
    sM[tid] = kmax; sN[tid] = kmin;
    __syncthreads();
    for (int off = 128; off; off >>= 1) {
        if (tid < off) {
            if (sM[tid + off] > sM[tid]) sM[tid] = sM[tid + off];
            if (sN[tid + off] < sN[tid]) sN[tid] = sN[tid + off];
        }
        __syncthreads();
    }
    const ull km = sM[0], kn = sN[0];
    const float ap = __uint_as_float((unsigned)(km >> 32));
    const int p = (int)(unsigned)(km & 0xFFFFFFFFu);
    const float an = __uint_as_float((unsigned)(kn >> 32));
    const int q = (int)~(unsigned)(kn & 0xFFFFFFFFu);
    __syncthreads();

    const int lq = tgt[q];
    const float* rowq = D + (size_t)q * N_DIM;
    ull kr = ~0ULL;
#pragma unroll
    for (int it = 0; it < 4; ++it) {
        const int j0 = (it * 256 + tid) * 4;
        floatx4 d = *(const floatx4*)(rowq + j0);
        intx4 t4 = *(const intx4*)(tgt + j0);
#pragma unroll
        for (int e = 0; e < 4; ++e) {
            const int j = j0 + e;
            if (t4[e] != ti && t4[e] != lq) {
                ull k = ((ull)__float_as_uint(d[e]) << 32) | (unsigned)~j;
                if (k < kr) kr = k;
            }
        }
    }
    sN[tid] = kr;
    __syncthreads();
    for (int off = 128; off; off >>= 1) {
        if (tid < off) { if (sN[tid + off] < sN[tid]) sN[tid] = sN[tid + off]; }
        __syncthreads();
    }
    if (tid == 0) {
        const ull kk = sN[0];
        const float okmin = __uint_as_float((unsigned)(kk >> 32));
        const int r = (int)~(unsigned)(kk & 0xFFFFFFFFu);
        const float an2 = D[(size_t)p * N_DIM + q];
        const float an3 = D[(size_t)i * N_DIM + r];
        lossArr[i] = fmaxf(ap - an, 0.f) + fabsf(an - an2) + fabsf(an3 - okmin);
    }
}

// ---------------- Kernel 3: final sum / n -----------------------------------
__global__ __launch_bounds__(256)
void finred(const float* __restrict__ lossArr, float* __restrict__ out) {
    const int tid = threadIdx.x;
    float s = 0.f;
    for (int j = tid; j < N_DIM; j += 256) s += lossArr[j];
#pragma unroll
    for (int off = 32; off; off >>= 1) s += __shfl_down(s, off);
    __shared__ float w[4];
    const int wave = tid >> 6, lane = tid & 63;
    if (lane == 0) w[wave] = s;
    __syncthreads();
    if (tid == 0) out[0] = (w[0] + w[1] + w[2] + w[3]) * (1.0f / (float)N_DIM);
}

extern "C" void kernel_launch(void* const* d_in, const int* in_sizes, int n_in,
                              void* d_out, int out_size, void* d_ws, size_t ws_size,
                              hipStream_t stream) {
    const float* X = (const float*)d_in[0];
    const int* tgt = (const int*)d_in[1];
    float* out = (float*)d_out;

    char* w = (char*)d_ws;
    char* Q = w;                                              // 8 MB int8
    float* D = (float*)(w + ((size_t)16 << 20));              // 64 MB
    int* sqi = (int*)(w + ((size_t)80 << 20));                // 16 KB
    float* lossArr = (float*)(sqi + N_DIM);                   // 16 KB

    prep_kernel<<<N_DIM, 256, 0, stream>>>(X, Q, sqi);
    gemm_dist<<<1024, 256, 0, stream>>>(Q, sqi, D);
    stats_loss<<<N_DIM, 256, 0, stream>>>(D, tgt, lossArr);
    finred<<<1, 256, 0, stream>>>(lossArr, out);
}

// Round 11
// 76.823 us; speedup vs baseline: 1.5446x; 1.5446x over previous
//
#include <hip/hip_runtime.h>
#include <hip/hip_bf16.h>
#include <cstdint>

#define N_DIM 4096
#define K_DIM 2048           // i8 elements per row
#define NKT 32               // 32 K-tiles of 64
#define QSCALE 24.0f
#define QINV (1.0f / 24.0f)

typedef float floatx4 __attribute__((ext_vector_type(4)));
typedef int intx4 __attribute__((ext_vector_type(4)));
typedef unsigned short ushort8 __attribute__((ext_vector_type(8)));
typedef unsigned long long ull;

__device__ __forceinline__ unsigned short f2bf(float f) {
    unsigned int u = __builtin_bit_cast(unsigned int, f);
    unsigned int r = (u + 0x7fffu + ((u >> 16) & 1u)) >> 16;  // RNE
    return (unsigned short)r;
}

__device__ __forceinline__ float bf2f(unsigned short b) {
    return __uint_as_float(((unsigned)b) << 16);
}

__device__ __forceinline__ void gld_lds16(const void* g, void* l) {
    __builtin_amdgcn_global_load_lds(
        (const __attribute__((address_space(1))) unsigned int*)g,
        (__attribute__((address_space(3))) unsigned int*)l,
        16, 0, 0);
}

// ---- Kernel 0: quantize fp32 -> int8 (scale 24) into k-major panels --------
// Qt layout: byte(kslot, row) = (kslot*4096 + row)*16, kslot = k/16 (0..127).
// This makes gemm staging sources CONSECUTIVE across lanes (coalesced).
__global__ __launch_bounds__(256)
void prep_kernel(const float* __restrict__ X, char* __restrict__ Qt,
                 int* __restrict__ sqi) {
    const int row = blockIdx.x;
    const int tid = threadIdx.x;
    const float* xr = X + (size_t)row * K_DIM;
    floatx4 a = *(const floatx4*)(xr + tid * 8);
    floatx4 b = *(const floatx4*)(xr + tid * 8 + 4);
    int s = 0;
    unsigned lo = 0, hi = 0;
#pragma unroll
    for (int e = 0; e < 4; ++e) {
        int v = __float2int_rn(a[e] * QSCALE);
        v = min(127, max(-127, v));
        s += v * v;
        lo |= ((unsigned)(v & 0xff)) << (8 * e);
        int w = __float2int_rn(b[e] * QSCALE);
        w = min(127, max(-127, w));
        s += w * w;
        hi |= ((unsigned)(w & 0xff)) << (8 * e);
    }
    // k0 = tid*8 -> kslot = tid>>1, byte-within-16 = (tid&1)*8
    *(int2*)(Qt + ((size_t)(tid >> 1) * 4096 + row) * 16 + (tid & 1) * 8) =
        make_int2((int)lo, (int)hi);
#pragma unroll
    for (int off = 32; off; off >>= 1) s += __shfl_down(s, off);
    __shared__ int wsum[4];
    const int wave = tid >> 6, lane = tid & 63;
    if (lane == 0) wsum[wave] = s;
    __syncthreads();
    if (tid == 0) sqi[row] = wsum[0] + wsum[1] + wsum[2] + wsum[3];
}

// ---- Kernel 1: 256x256 int8 MFMA GEMM + bf16 distance epilogue -------------
// R9-proven structure (absmax-verified, 0 bank conflicts): 512 thr = 8 waves
// (2Mx4N), mfma_i32_16x16x64_i8, triple-buffered 96KB LDS, 2 phases/K-tile:
//   ph1: RD Alo(4)+B(4) | STG B0,B1(t+2) | BAR | 16 MFMA (MH=0)
//   ph2: RD Ahi(4)      | STG A0,A1(t+2) | vmcnt(4) | BAR | 16 MFMA (MH=1)
// NEW vs R9: staging sources read the k-major Qt panels -> consecutive lanes
// read consecutive 16B (coalesced; was 2KB-strided = 64 lines/instr).
// LDS region (8KB) holds pos16 = kslot*128 + row; reads conflict-free.
// D stored as bf16 (halves write + downstream read traffic).
#define BAR() __builtin_amdgcn_s_barrier()
#define PRIO1() __builtin_amdgcn_s_setprio(1)
#define PRIO0() __builtin_amdgcn_s_setprio(0)
#define VMCNT4() asm volatile("s_waitcnt vmcnt(4)" ::: "memory")
#define VMCNT0() asm volatile("s_waitcnt vmcnt(0)" ::: "memory")
#define MM8(MHI, AF) { _Pragma("unroll") for (int n_ = 0; n_ < 4; ++n_) { \
    _Pragma("unroll") for (int m_ = 0; m_ < 4; ++m_) { \
        acc[MHI][n_][m_] = __builtin_amdgcn_mfma_i32_16x16x64_i8( \
            AF[m_], bfv[n_], acc[MHI][n_][m_], 0, 0, 0); } } }
// one K-tile advance in Qt = 4 kslots = 4*4096*16 bytes
#define KTB 262144
#define STG_B(KT, BB) { \
    gld_lds16(bSt + (size_t)(KT) * KTB,        lds + (BB) + 16384 + widB); \
    gld_lds16(bSt + (size_t)(KT) * KTB + 2048, lds + (BB) + 24576 + widB); }
#define STG_A(KT, BB) { \
    gld_lds16(aSt + (size_t)(KT) * KTB,        lds + (BB) + widB); \
    gld_lds16(aSt + (size_t)(KT) * KTB + 2048, lds + (BB) + 8192 + widB); }

__global__ __launch_bounds__(512, 2)
void gemm_dist(const char* __restrict__ Qt, const int* __restrict__ sqi,
               unsigned short* __restrict__ Db) {
    __shared__ char lds[98304];   // 96 KB = 3 bufs x (A0,A1,B0,B1 of 8KB)
    const int tid = threadIdx.x;
    const int wid = tid >> 6, lane = tid & 63;
    const int wr = wid >> 2, wc = wid & 3;
    const int fr = lane & 15, ksub = lane >> 4;
    const int widB = wid * 1024;

    int rA[4], rB[4];
#pragma unroll
    for (int m = 0; m < 4; ++m) rA[m] = (ksub * 128 + m * 16 + fr) * 16;
#pragma unroll
    for (int n = 0; n < 4; ++n) rB[n] = (ksub * 128 + (wc & 1) * 64 + n * 16 + fr) * 16;
    const int aRegOff = wr * 8192;
    const int bRegOff = 16384 + (wc >> 1) * 8192;

    const int swz = (blockIdx.x & 7) * 32 + (blockIdx.x >> 3);  // XCD-chunked
    const int bi = swz >> 4, bj = swz & 15;
    const int rowC0 = bi * 256, colC0 = bj * 256;

    // staging source: thread tid covers pos16 = tid -> kslot = tid>>7,
    // row = tid&127; Qt byte = (kslot*4096 + rowBase + row)*16 (coalesced).
    const int srow = tid & 127;
    const int sks = tid >> 7;
    const char* aSt = Qt + ((size_t)sks * 4096 + rowC0 + srow) * 16;
    const char* bSt = Qt + ((size_t)sks * 4096 + colC0 + srow) * 16;

    intx4 acc[2][4][4];
#pragma unroll
    for (int a0 = 0; a0 < 2; ++a0)
#pragma unroll
    for (int a1 = 0; a1 < 4; ++a1)
#pragma unroll
    for (int a2 = 0; a2 < 4; ++a2) acc[a0][a1][a2] = (intx4){0, 0, 0, 0};
    intx4 aflo[4], afhi[4], bfv[4];

    // prologue: t0 (4 loads) then t1 (4); vmcnt(4) = t0 landed
    STG_B(0, 0); STG_A(0, 0);
    STG_B(1, 32768); STG_A(1, 32768);
    VMCNT4();
    BAR();

    int cb = 0, sb = 65536;   // current / staging(t+2) buffer byte base
    for (int t = 0; t < NKT; ++t) {
        const bool pf = (t < NKT - 2);
        const char* bufA = lds + cb + aRegOff;
        const char* bufBp = lds + cb + bRegOff;
        // ph1: RD Alo + B | STG (t+2).B0,B1 | BAR | MFMA MH=0
#pragma unroll
        for (int m = 0; m < 4; ++m) aflo[m] = *(const intx4*)(bufA + rA[m]);
#pragma unroll
        for (int n = 0; n < 4; ++n) bfv[n] = *(const intx4*)(bufBp + rB[n]);
        if (pf) STG_B(t + 2, sb);
        BAR(); PRIO1(); MM8(0, aflo); PRIO0();
        // ph2: RD Ahi | STG (t+2).A0,A1 | vmcnt | BAR | MFMA MH=1
#pragma unroll
        for (int m = 0; m < 4; ++m) afhi[m] = *(const intx4*)(bufA + 1024 + rA[m]);
        if (pf) { STG_A(t + 2, sb); VMCNT4(); } else { VMCNT0(); }
        BAR(); PRIO1(); MM8(1, afhi); PRIO0();
        cb += 32768; if (cb >= 98304) cb = 0;
        sb += 32768; if (sb >= 98304) sb = 0;
    }

    // epilogue: D[i][j] = bf16( (v>0) ? sqrt(v)/24 : 1e-6 ), v exact int32
#pragma unroll
    for (int MH = 0; MH < 2; ++MH)
#pragma unroll
    for (int n = 0; n < 4; ++n) {
        const int col = colC0 + wc * 64 + n * 16 + fr;
        const int sqc = sqi[col];
#pragma unroll
        for (int m = 0; m < 4; ++m) {
            const int row0 = rowC0 + wr * 128 + MH * 64 + m * 16 + ksub * 4;
#pragma unroll
            for (int r = 0; r < 4; ++r) {
                const int v = sqi[row0 + r] + sqc - 2 * acc[MH][n][m][r];
                const float d = (v > 0) ? sqrtf((float)v) * QINV : 1e-6f;
                Db[(size_t)(row0 + r) * N_DIM + col] = f2bf(d);
            }
        }
    }
}

// ---- Kernel 2: fused row stats + third-class scan + loss (bf16 D) ----------
__global__ __launch_bounds__(256)
void stats_loss(const unsigned short* __restrict__ Db, const int* __restrict__ tgt,
                float* __restrict__ lossArr) {
    const int i = blockIdx.x, tid = threadIdx.x;
    const int ti = tgt[i];
    const unsigned short* row = Db + (size_t)i * N_DIM;
    ull kmax = 0ULL, kmin = ~0ULL;
#pragma unroll
    for (int it = 0; it < 2; ++it) {
        const int j0 = (it * 256 + tid) * 8;
        ushort8 d = *(const ushort8*)(row + j0);
        intx4 ta = *(const intx4*)(tgt + j0);
        intx4 tb = *(const intx4*)(tgt + j0 + 4);
#pragma unroll
        for (int e = 0; e < 8; ++e) {
            const int j = j0 + e;
            const int tl = (e < 4) ? ta[e] : tb[e - 4];
            const ull db = (ull)d[e] << 32;
            if (tl == ti) { ull k = db | (unsigned)j;  if (k > kmax) kmax = k; }
            else          { ull k = db | (unsigned)~j; if (k < kmin) kmin = k; }
        }
    }
    __shared__ ull sM[256], sN[256];
    sM[tid] = kmax; sN[tid] = kmin;
    __syncthreads();
    for (int off = 128; off; off >>= 1) {
        if (tid < off) {
            if (sM[tid + off] > sM[tid]) sM[tid] = sM[tid + off];
            if (sN[tid + off] < sN[tid]) sN[tid] = sN[tid + off];
        }
        __syncthreads();
    }
    const ull km = sM[0], kn = sN[0];
    const float ap = bf2f((unsigned short)(km >> 32));
    const int p = (int)(unsigned)(km & 0xFFFFFFFFu);
    const float an = bf2f((unsigned short)(kn >> 32));
    const int q = (int)~(unsigned)(kn & 0xFFFFFFFFu);
    __syncthreads();

    const int lq = tgt[q];
    const unsigned short* rowq = Db + (size_t)q * N_DIM;
    ull kr = ~0ULL;
#pragma unroll
    for (int it = 0; it < 2; ++it) {
        const int j0 = (it * 256 + tid) * 8;
        ushort8 d = *(const ushort8*)(rowq + j0);
        intx4 ta = *(const intx4*)(tgt + j0);
        intx4 tb = *(const intx4*)(tgt + j0 + 4);
#pragma unroll
        for (int e = 0; e < 8; ++e) {
            const int j = j0 + e;
            const int tl = (e < 4) ? ta[e] : tb[e - 4];
            if (tl != ti && tl != lq) {
                ull k = ((ull)d[e] << 32) | (unsigned)~j;
                if (k < kr) kr = k;
            }
        }
    }
    sN[tid] = kr;
    __syncthreads();
    for (int off = 128; off; off >>= 1) {
        if (tid < off) { if (sN[tid + off] < sN[tid]) sN[tid] = sN[tid + off]; }
        __syncthreads();
    }
    if (tid == 0) {
        const ull kk = sN[0];
        const float okmin = bf2f((unsigned short)(kk >> 32));
        const int r = (int)~(unsigned)(kk & 0xFFFFFFFFu);
        const float an2 = bf2f(Db[(size_t)p * N_DIM + q]);
        const float an3 = bf2f(Db[(size_t)i * N_DIM + r]);
        lossArr[i] = fmaxf(ap - an, 0.f) + fabsf(an - an2) + fabsf(an3 - okmin);
    }
}

// ---- Kernel 3: final sum / n ------------------------------------------------
__global__ __launch_bounds__(256)
void finred(const float* __restrict__ lossArr, float* __restrict__ out) {
    const int tid = threadIdx.x;
    float s = 0.f;
    for (int j = tid; j < N_DIM; j += 256) s += lossArr[j];
#pragma unroll
    for (int off = 32; off; off >>= 1) s += __shfl_down(s, off);
    __shared__ float w[4];
    const int wave = tid >> 6, lane = tid & 63;
    if (lane == 0) w[wave] = s;
    __syncthreads();
    if (tid == 0) out[0] = (w[0] + w[1] + w[2] + w[3]) * (1.0f / (float)N_DIM);
}

extern "C" void kernel_launch(void* const* d_in, const int* in_sizes, int n_in,
                              void* d_out, int out_size, void* d_ws, size_t ws_size,
                              hipStream_t stream) {
    const float* X = (const float*)d_in[0];
    const int* tgt = (const int*)d_in[1];
    float* out = (float*)d_out;

    char* w = (char*)d_ws;
    char* Qt = w;                                             // 8 MB (k-major)
    unsigned short* Db = (unsigned short*)(w + ((size_t)16 << 20));  // 32 MB bf16
    int* sqi = (int*)(w + ((size_t)80 << 20));                // 16 KB
    float* lossArr = (float*)(sqi + N_DIM);                   // 16 KB

    prep_kernel<<<N_DIM, 256, 0, stream>>>(X, Qt, sqi);
    gemm_dist<<<256, 512, 0, stream>>>(Qt, sqi, Db);
    stats_loss<<<N_DIM, 256, 0, stream>>>(Db, tgt, lossArr);
    finred<<<1, 256, 0, stream>>>(lossArr, out);
}